// Round 5
// baseline (621.116 us; speedup 1.0000x reference)
//
#include <hip/hip_runtime.h>

#define BI 4
#define TT 2048
#define EE 1024
#define HH 16
#define DD 64
// M = BI*TT = 8192

typedef short bf16x8 __attribute__((ext_vector_type(8)));
typedef float f32x4 __attribute__((ext_vector_type(4)));
typedef unsigned short u16;

#define AS1 __attribute__((address_space(1)))
#define AS3 __attribute__((address_space(3)))
#define GLOADLDS16(g, l) __builtin_amdgcn_global_load_lds((const AS1 void*)(g), (AS3 void*)(l), 16, 0, 0)

__device__ __forceinline__ u16 f2bf(float f) {
    unsigned int u = __builtin_bit_cast(unsigned int, f);
    unsigned int r = (u + 0x7fffu + ((u >> 16) & 1u)) >> 16;
    return (u16)r;
}
// pack float4 -> 4 bf16 (RNE) via v_cvt_pk_bf16_f32
__device__ __forceinline__ uint2 pk4(float4 x) {
    uint2 r;
    asm("v_cvt_pk_bf16_f32 %0, %1, %2" : "=v"(r.x) : "v"(x.x), "v"(x.y));
    asm("v_cvt_pk_bf16_f32 %0, %1, %2" : "=v"(r.y) : "v"(x.z), "v"(x.w));
    return r;
}

// ---------------- Kernel 1: fused QKV projection ----------------
// One block per (128-row m-panel, head): stages data tile ONCE, computes
// q (scaled 0.125), k (row-major [b][h][t][d]) and vT ([b][h][d][t]).
__global__ __launch_bounds__(256) void qkv_gemm(
    const float* __restrict__ data, const float* __restrict__ Wq,
    const float* __restrict__ Wk, const float* __restrict__ Wv,
    u16* __restrict__ qws, u16* __restrict__ kws, u16* __restrict__ vtws)
{
    const int h  = blockIdx.y;
    const int m0 = blockIdx.x * 128;
    const int b  = m0 / TT;
    const int t0 = m0 % TT;

    __shared__ u16 As[128][72];      // data tile [t-row][e]
    __shared__ u16 Bs[3][64][72];    // W^T tiles [z][d][e]

    const int tid = threadIdx.x;
    const int l  = tid & 63;
    const int w  = tid >> 6;
    const int wr = w >> 1;
    const int wc = w & 1;
    const int lr = l & 15;
    const int lk = l >> 4;

    f32x4 acc[3][4][2];
    for (int z = 0; z < 3; ++z)
        for (int i = 0; i < 4; ++i)
            for (int j = 0; j < 2; ++j)
                acc[z][i][j] = (f32x4){0.f, 0.f, 0.f, 0.f};

    for (int e0 = 0; e0 < EE; e0 += 64) {
        // stage A: 128x64 f32 -> bf16 (float4 loads + cvt_pk)
        const float* dsrc = data + (size_t)m0 * EE + e0;
        for (int it = 0; it < 8; ++it) {
            int v = tid + it * 256;
            int row = v >> 4, c4 = v & 15;
            float4 x = *reinterpret_cast<const float4*>(dsrc + (size_t)row * EE + c4 * 4);
            *reinterpret_cast<uint2*>(&As[row][c4 * 4]) = pk4(x);
        }
        // stage B^T for all three z
        #pragma unroll
        for (int z = 0; z < 3; ++z) {
            const float* W = (z == 0) ? Wq : ((z == 1) ? Wk : Wv);
            const float* wsrc = W + ((size_t)h * EE + e0) * DD;
            for (int it = 0; it < 4; ++it) {
                int v = tid + it * 256;
                int e = v >> 4, d4 = v & 15;
                float4 x = *reinterpret_cast<const float4*>(wsrc + (size_t)e * DD + d4 * 4);
                Bs[z][d4 * 4 + 0][e] = f2bf(x.x);
                Bs[z][d4 * 4 + 1][e] = f2bf(x.y);
                Bs[z][d4 * 4 + 2][e] = f2bf(x.z);
                Bs[z][d4 * 4 + 3][e] = f2bf(x.w);
            }
        }
        __syncthreads();
        for (int kk = 0; kk < 64; kk += 32) {
            bf16x8 a[4];
            #pragma unroll
            for (int fr = 0; fr < 4; ++fr)
                a[fr] = *reinterpret_cast<const bf16x8*>(&As[wr * 64 + fr * 16 + lr][kk + lk * 8]);
            #pragma unroll
            for (int z = 0; z < 3; ++z) {
                bf16x8 b0 = *reinterpret_cast<const bf16x8*>(&Bs[z][wc * 32 + lr][kk + lk * 8]);
                bf16x8 b1 = *reinterpret_cast<const bf16x8*>(&Bs[z][wc * 32 + 16 + lr][kk + lk * 8]);
                if (z == 2) {
                    #pragma unroll
                    for (int fr = 0; fr < 4; ++fr) {
                        acc[2][fr][0] = __builtin_amdgcn_mfma_f32_16x16x32_bf16(b0, a[fr], acc[2][fr][0], 0, 0, 0);
                        acc[2][fr][1] = __builtin_amdgcn_mfma_f32_16x16x32_bf16(b1, a[fr], acc[2][fr][1], 0, 0, 0);
                    }
                } else {
                    #pragma unroll
                    for (int fr = 0; fr < 4; ++fr) {
                        acc[z][fr][0] = __builtin_amdgcn_mfma_f32_16x16x32_bf16(a[fr], b0, acc[z][fr][0], 0, 0, 0);
                        acc[z][fr][1] = __builtin_amdgcn_mfma_f32_16x16x32_bf16(a[fr], b1, acc[z][fr][1], 0, 0, 0);
                    }
                }
            }
        }
        __syncthreads();
    }

    // epilogue z=0 (q, scaled) and z=1 (k): [b][h][t][d]
    #pragma unroll
    for (int z = 0; z < 2; ++z) {
        u16* out = (z == 0) ? qws : kws;
        const float scale = (z == 0) ? 0.125f : 1.0f;
        for (int fr = 0; fr < 4; ++fr) {
            int row = wr * 64 + fr * 16 + lk * 4;
            for (int fc = 0; fc < 2; ++fc) {
                int col = wc * 32 + fc * 16 + lr;
                size_t base = (((size_t)b * HH + h) * TT + (size_t)(t0 + row)) * DD + col;
                for (int rr = 0; rr < 4; ++rr)
                    out[base + (size_t)rr * DD] = f2bf(acc[z][fr][fc][rr] * scale);
            }
        }
    }
    // epilogue z=2 (vT): [b][h][d][t]; acc row = d, col = t
    for (int fr = 0; fr < 4; ++fr) {
        int tcol = wr * 64 + fr * 16 + lr;
        for (int fc = 0; fc < 2; ++fc) {
            int drow = wc * 32 + fc * 16 + lk * 4;
            size_t base = (((size_t)(b * HH + h)) * DD + drow) * TT + (t0 + tcol);
            for (int rr = 0; rr < 4; ++rr)
                vtws[base + (size_t)rr * TT] = f2bf(acc[2][fr][fc][rr]);
        }
    }
}

// ---------------- Kernel 2: causal flash attention v3 ----------------
// QBLK=128 (4 waves x 32 q-rows), KVBLK=64, double-buffered global_load_lds,
// XOR-swizzled LDS reads, setprio around MFMA clusters.
__global__ __launch_bounds__(256) void attn(
    const u16* __restrict__ qws, const u16* __restrict__ kws,
    const u16* __restrict__ vtws, u16* __restrict__ aout)
{
    const int qt = 15 - (int)blockIdx.x;  // reversed: heaviest first
    const int bh = blockIdx.y;
    const int b = bh >> 4, h = bh & 15;
    const int q0 = qt * 128;

    __shared__ u16 Ks[2][64 * 64];    // K tile [s][d], swizzled content
    __shared__ u16 Vs[2][64 * 64];    // vT tile [d][s], swizzled content
    __shared__ u16 Pb[4][32 * 68];    // per-wave P round-trip, stride 68

    const int tid = threadIdx.x;
    const int l = tid & 63;
    const int w = tid >> 6;
    const int lr = l & 15, lk = l >> 4;
    const int lrow = l >> 3, lslot = l & 7;

    const size_t kvbase = (size_t)bh * TT * DD;
    const int qb = q0 + w * 32;       // this wave's 32 q-rows

    bf16x8 qf[2][2];
    #pragma unroll
    for (int fr = 0; fr < 2; ++fr)
        for (int kk = 0; kk < 2; ++kk)
            qf[fr][kk] = *reinterpret_cast<const bf16x8*>(
                qws + kvbase + (size_t)(qb + fr * 16 + lr) * DD + kk * 32 + lk * 8);
    asm volatile("s_waitcnt vmcnt(0)" ::: "memory");

    auto stage = [&](int jt, int bufi) {
        const int s0 = jt * 64;
        for (int ii = 0; ii < 2; ++ii) {
            const int row = w * 16 + ii * 8 + lrow;       // 0..63
            const int sw = lslot ^ (row & 7);
            const u16* gk = kws + kvbase + (size_t)(s0 + row) * DD + sw * 8;
            GLOADLDS16(gk, &Ks[bufi][(w * 16 + ii * 8) * 64]);
            const u16* gv = vtws + kvbase + (size_t)row * TT + s0 + sw * 8;
            GLOADLDS16(gv, &Vs[bufi][(w * 16 + ii * 8) * 64]);
        }
    };

    f32x4 oacc[2][4];
    #pragma unroll
    for (int fr = 0; fr < 2; ++fr)
        for (int i = 0; i < 4; ++i) oacc[fr][i] = (f32x4){0.f, 0.f, 0.f, 0.f};
    float mrow[2][4], lsum[2][4];
    for (int fr = 0; fr < 2; ++fr)
        for (int r = 0; r < 4; ++r) { mrow[fr][r] = -INFINITY; lsum[fr][r] = 0.f; }

    const int ntiles = 2 * qt + 2;
    stage(0, 0);

    for (int j = 0; j < ntiles; ++j) {
        const int cur = j & 1;
        if (j + 1 < ntiles) {
            stage(j + 1, cur ^ 1);
            asm volatile("s_waitcnt vmcnt(4)" ::: "memory");
        } else {
            asm volatile("s_waitcnt vmcnt(0)" ::: "memory");
        }
        __builtin_amdgcn_sched_barrier(0);
        __builtin_amdgcn_s_barrier();
        __builtin_amdgcn_sched_barrier(0);

        const int s0 = j * 64;
        const u16* Kb = &Ks[cur][0];
        const u16* Vb = &Vs[cur][0];

        if (s0 <= qb + 31) {              // wave has unmasked work
            // QK^T
            f32x4 sc[2][4];
            #pragma unroll
            for (int fr = 0; fr < 2; ++fr)
                for (int fc = 0; fc < 4; ++fc)
                    sc[fr][fc] = (f32x4){0.f, 0.f, 0.f, 0.f};
            __builtin_amdgcn_s_setprio(1);
            #pragma unroll
            for (int fc = 0; fc < 4; ++fc) {
                const int row = fc * 16 + lr;
                const int sw = (row & 7) << 3;
                #pragma unroll
                for (int kk = 0; kk < 2; ++kk) {
                    bf16x8 kf = *reinterpret_cast<const bf16x8*>(Kb + row * 64 + ((kk * 32 + lk * 8) ^ sw));
                    sc[0][fc] = __builtin_amdgcn_mfma_f32_16x16x32_bf16(qf[0][kk], kf, sc[0][fc], 0, 0, 0);
                    sc[1][fc] = __builtin_amdgcn_mfma_f32_16x16x32_bf16(qf[1][kk], kf, sc[1][fc], 0, 0, 0);
                }
            }
            __builtin_amdgcn_s_setprio(0);
            // causal mask only near the diagonal
            if (s0 + 63 > qb) {
                #pragma unroll
                for (int fr = 0; fr < 2; ++fr)
                    for (int fc = 0; fc < 4; ++fc)
                        for (int r = 0; r < 4; ++r)
                            if (s0 + fc * 16 + lr > qb + fr * 16 + lk * 4 + r)
                                sc[fr][fc][r] = -INFINITY;
            }
            // online softmax (16-lane row groups)
            float mx[2][4];
            #pragma unroll
            for (int fr = 0; fr < 2; ++fr)
                for (int r = 0; r < 4; ++r)
                    mx[fr][r] = fmaxf(fmaxf(sc[fr][0][r], sc[fr][1][r]), fmaxf(sc[fr][2][r], sc[fr][3][r]));
            for (int off = 1; off < 16; off <<= 1)
                #pragma unroll
                for (int fr = 0; fr < 2; ++fr)
                    for (int r = 0; r < 4; ++r)
                        mx[fr][r] = fmaxf(mx[fr][r], __shfl_xor(mx[fr][r], off, 64));
            float alpha[2][4];
            #pragma unroll
            for (int fr = 0; fr < 2; ++fr)
                for (int r = 0; r < 4; ++r) {
                    float mnew = fmaxf(mrow[fr][r], mx[fr][r]);
                    alpha[fr][r] = exp2f((mrow[fr][r] - mnew) * 1.44269504f);
                    mrow[fr][r] = mnew;
                }
            float rsum[2][4];
            #pragma unroll
            for (int fr = 0; fr < 2; ++fr)
                for (int r = 0; r < 4; ++r) rsum[fr][r] = 0.f;
            #pragma unroll
            for (int fr = 0; fr < 2; ++fr)
                for (int fc = 0; fc < 4; ++fc)
                    for (int r = 0; r < 4; ++r) {
                        float p = exp2f((sc[fr][fc][r] - mrow[fr][r]) * 1.44269504f);
                        sc[fr][fc][r] = p;
                        rsum[fr][r] += p;
                    }
            for (int off = 1; off < 16; off <<= 1)
                #pragma unroll
                for (int fr = 0; fr < 2; ++fr)
                    for (int r = 0; r < 4; ++r)
                        rsum[fr][r] += __shfl_xor(rsum[fr][r], off, 64);
            #pragma unroll
            for (int fr = 0; fr < 2; ++fr)
                for (int r = 0; r < 4; ++r)
                    lsum[fr][r] = lsum[fr][r] * alpha[fr][r] + rsum[fr][r];
            #pragma unroll
            for (int fr = 0; fr < 2; ++fr)
                for (int fc = 0; fc < 4; ++fc)
                    for (int r = 0; r < 4; ++r)
                        oacc[fr][fc][r] *= alpha[fr][r];
            // P -> LDS (stride 68, 2-way free) -> A-fragment
            #pragma unroll
            for (int fr = 0; fr < 2; ++fr)
                for (int fc = 0; fc < 4; ++fc)
                    for (int r = 0; r < 4; ++r)
                        Pb[w][(fr * 16 + lk * 4 + r) * 68 + fc * 16 + lr] = f2bf(sc[fr][fc][r]);
            bf16x8 pa[2][2];
            #pragma unroll
            for (int fr = 0; fr < 2; ++fr)
                for (int ks = 0; ks < 2; ++ks)
                    pa[fr][ks] = *reinterpret_cast<const bf16x8*>(&Pb[w][(fr * 16 + lr) * 68 + ks * 32 + lk * 8]);
            // PV
            __builtin_amdgcn_s_setprio(1);
            #pragma unroll
            for (int fc = 0; fc < 4; ++fc) {
                const int row = fc * 16 + lr;
                const int sw = (row & 7) << 3;
                #pragma unroll
                for (int ks = 0; ks < 2; ++ks) {
                    bf16x8 vf = *reinterpret_cast<const bf16x8*>(Vb + row * 64 + ((ks * 32 + lk * 8) ^ sw));
                    oacc[0][fc] = __builtin_amdgcn_mfma_f32_16x16x32_bf16(pa[0][ks], vf, oacc[0][fc], 0, 0, 0);
                    oacc[1][fc] = __builtin_amdgcn_mfma_f32_16x16x32_bf16(pa[1][ks], vf, oacc[1][fc], 0, 0, 0);
                }
            }
            __builtin_amdgcn_s_setprio(0);
        }
        __builtin_amdgcn_sched_barrier(0);
        __builtin_amdgcn_s_barrier();
        __builtin_amdgcn_sched_barrier(0);
    }

    // epilogue: concat-head layout [b][t][h*64+d]
    #pragma unroll
    for (int fr = 0; fr < 2; ++fr)
        for (int fc = 0; fc < 4; ++fc) {
            int dcol = fc * 16 + lr;
            for (int r = 0; r < 4; ++r) {
                int qrow = qb + fr * 16 + lk * 4 + r;
                float v = oacc[fr][fc][r] / lsum[fr][r];
                aout[((size_t)b * TT + qrow) * EE + (size_t)h * DD + dcol] = f2bf(v);
            }
        }
}

// ---------------- Kernel 3: output projection + bias ----------------
__global__ __launch_bounds__(256) void proj_gemm(
    const u16* __restrict__ A, const float* __restrict__ Wp,
    const float* __restrict__ bp, float* __restrict__ out)
{
    const int m0 = blockIdx.x * 128;
    const int n0 = blockIdx.y * 64;

    __shared__ u16 As[128][72];
    __shared__ u16 Bs[64][72];

    const int tid = threadIdx.x;
    const int l  = tid & 63;
    const int w  = tid >> 6;
    const int wr = w >> 1;
    const int wc = w & 1;
    const int lr = l & 15;
    const int lk = l >> 4;

    f32x4 acc[4][2];
    for (int i = 0; i < 4; ++i)
        for (int j = 0; j < 2; ++j)
            acc[i][j] = (f32x4){0.f, 0.f, 0.f, 0.f};

    for (int e0 = 0; e0 < EE; e0 += 64) {
        const uint4* asrc = reinterpret_cast<const uint4*>(A);
        for (int it = 0; it < 4; ++it) {
            int v = tid + it * 256;
            int row = v >> 3, c8 = v & 7;
            uint4 x = asrc[(((size_t)(m0 + row)) * EE + e0) / 8 + c8];
            *reinterpret_cast<uint4*>(&As[row][c8 * 8]) = x;
        }
        const float* wsrc = Wp + (size_t)e0 * EE + n0;
        for (int it = 0; it < 4; ++it) {
            int v = tid + it * 256;
            int e = v >> 4, n4 = v & 15;
            float4 x = *reinterpret_cast<const float4*>(wsrc + (size_t)e * EE + n4 * 4);
            Bs[n4 * 4 + 0][e] = f2bf(x.x);
            Bs[n4 * 4 + 1][e] = f2bf(x.y);
            Bs[n4 * 4 + 2][e] = f2bf(x.z);
            Bs[n4 * 4 + 3][e] = f2bf(x.w);
        }
        __syncthreads();
        for (int kk = 0; kk < 64; kk += 32) {
            bf16x8 a[4], bb[2];
            for (int fr = 0; fr < 4; ++fr)
                a[fr] = *reinterpret_cast<const bf16x8*>(&As[wr * 64 + fr * 16 + lr][kk + lk * 8]);
            for (int fc = 0; fc < 2; ++fc)
                bb[fc] = *reinterpret_cast<const bf16x8*>(&Bs[wc * 32 + fc * 16 + lr][kk + lk * 8]);
            for (int fr = 0; fr < 4; ++fr)
                for (int fc = 0; fc < 2; ++fc)
                    acc[fr][fc] = __builtin_amdgcn_mfma_f32_16x16x32_bf16(a[fr], bb[fc], acc[fr][fc], 0, 0, 0);
        }
        __syncthreads();
    }

    for (int fr = 0; fr < 4; ++fr) {
        int row = wr * 64 + fr * 16 + lk * 4;
        for (int fc = 0; fc < 2; ++fc) {
            int col = n0 + wc * 32 + fc * 16 + lr;
            float bias = bp[col];
            for (int rr = 0; rr < 4; ++rr)
                out[((size_t)(m0 + row + rr)) * EE + col] = acc[fr][fc][rr] + bias;
        }
    }
}

extern "C" void kernel_launch(void* const* d_in, const int* in_sizes, int n_in,
                              void* d_out, int out_size, void* d_ws, size_t ws_size,
                              hipStream_t stream) {
    const float* data = (const float*)d_in[0];
    const float* Wq   = (const float*)d_in[1];
    const float* Wk   = (const float*)d_in[2];
    const float* Wv   = (const float*)d_in[3];
    const float* Wp   = (const float*)d_in[4];
    const float* bp   = (const float*)d_in[5];
    float* outp = (float*)d_out;

    const size_t S = (size_t)BI * HH * TT * DD;  // 8,388,608 elems per buffer
    u16* qws = (u16*)d_ws;
    u16* kws = qws + S;
    u16* vtws = kws + S;   // [B][H][D][T]
    u16* aws  = vtws + S;

    qkv_gemm<<<dim3(64, 16), 256, 0, stream>>>(data, Wq, Wk, Wv, qws, kws, vtws);
    attn<<<dim3(16, 64), 256, 0, stream>>>(qws, kws, vtws, aws);
    proj_gemm<<<dim3(64, 16), 256, 0, stream>>>(aws, Wp, bp, outp);
}

// Round 6
// 350.325 us; speedup vs baseline: 1.7730x; 1.7730x over previous
//
#include <hip/hip_runtime.h>

#define BI 4
#define TT 2048
#define EE 1024
#define HH 16
#define DD 64
// M = BI*TT = 8192

typedef short bf16x8 __attribute__((ext_vector_type(8)));
typedef float f32x4 __attribute__((ext_vector_type(4)));
typedef unsigned short u16;

#define AS1 __attribute__((address_space(1)))
#define AS3 __attribute__((address_space(3)))
#define GLOADLDS16(g, l) __builtin_amdgcn_global_load_lds((const AS1 void*)(g), (AS3 void*)(l), 16, 0, 0)

__device__ __forceinline__ u16 f2bf(float f) {
    unsigned int u = __builtin_bit_cast(unsigned int, f);
    unsigned int r = (u + 0x7fffu + ((u >> 16) & 1u)) >> 16;
    return (u16)r;
}
__device__ __forceinline__ uint2 pk4(float4 x) {
    uint2 r;
    asm("v_cvt_pk_bf16_f32 %0, %1, %2" : "=v"(r.x) : "v"(x.x), "v"(x.y));
    asm("v_cvt_pk_bf16_f32 %0, %1, %2" : "=v"(r.y) : "v"(x.z), "v"(x.w));
    return r;
}

// ---------------- Prep 0: data f32 [M,E] -> bf16 [M,E] ----------------
__global__ __launch_bounds__(256) void cvt_data(const float* __restrict__ in, u16* __restrict__ out) {
    const int g = blockIdx.x * 256 + threadIdx.x;     // 262144 threads
    #pragma unroll
    for (int it = 0; it < 4; ++it) {
        size_t base = ((size_t)g + (size_t)it * 262144) * 8;
        float4 x0 = *reinterpret_cast<const float4*>(in + base);
        float4 x1 = *reinterpret_cast<const float4*>(in + base + 4);
        uint2 p0 = pk4(x0), p1 = pk4(x1);
        uint4 pp = {p0.x, p0.y, p1.x, p1.y};
        *reinterpret_cast<uint4*>(out + base) = pp;
    }
}

// ---------------- Prep 1: W [H,E,D] f32 -> WT [H,D,E] bf16 (x3 mats) ----------------
__global__ __launch_bounds__(256) void transp_w(
    const float* __restrict__ Wq, const float* __restrict__ Wk, const float* __restrict__ Wv,
    u16* __restrict__ oq, u16* __restrict__ ok, u16* __restrict__ ov)
{
    const int bidx = blockIdx.x;                      // 768 blocks
    const int mat = bidx >> 8, h = (bidx >> 4) & 15, et = bidx & 15;
    const float* in = (mat == 0) ? Wq : ((mat == 1) ? Wk : Wv);
    u16* out = (mat == 0) ? oq : ((mat == 1) ? ok : ov);
    const float* ip = in + ((size_t)h * EE + et * 64) * DD;   // 64 e-rows, stride DD
    u16* op = out + (size_t)h * DD * EE + et * 64;            // 64 d-rows, stride EE
    __shared__ u16 T[64][72];
    const int tid = threadIdx.x;
    #pragma unroll
    for (int it = 0; it < 4; ++it) {
        int v = tid + it * 256;
        int r = v >> 4, c4 = v & 15;
        float4 x = *reinterpret_cast<const float4*>(ip + (size_t)r * DD + c4 * 4);
        T[r][c4 * 4 + 0] = f2bf(x.x); T[r][c4 * 4 + 1] = f2bf(x.y);
        T[r][c4 * 4 + 2] = f2bf(x.z); T[r][c4 * 4 + 3] = f2bf(x.w);
    }
    __syncthreads();
    #pragma unroll
    for (int it = 0; it < 2; ++it) {
        int v = tid + it * 256;
        int c = v >> 3, s = v & 7;
        u16 tmp[8];
        #pragma unroll
        for (int i2 = 0; i2 < 8; ++i2) tmp[i2] = T[s * 8 + i2][c];
        *reinterpret_cast<uint4*>(op + (size_t)c * EE + s * 8) = *reinterpret_cast<uint4*>(tmp);
    }
}

// ---------------- Prep 2: Wp [E,E] f32 -> WpT [E,E] bf16 ----------------
__global__ __launch_bounds__(256) void transp_p(const float* __restrict__ Wp, u16* __restrict__ outp)
{
    const int bidx = blockIdx.x;                      // 256 blocks
    const int tr = bidx >> 4, tc = bidx & 15;
    const float* ip = Wp + ((size_t)tr * 64) * EE + tc * 64;
    u16* op = outp + ((size_t)tc * 64) * EE + tr * 64;
    __shared__ u16 T[64][72];
    const int tid = threadIdx.x;
    #pragma unroll
    for (int it = 0; it < 4; ++it) {
        int v = tid + it * 256;
        int r = v >> 4, c4 = v & 15;
        float4 x = *reinterpret_cast<const float4*>(ip + (size_t)r * EE + c4 * 4);
        T[r][c4 * 4 + 0] = f2bf(x.x); T[r][c4 * 4 + 1] = f2bf(x.y);
        T[r][c4 * 4 + 2] = f2bf(x.z); T[r][c4 * 4 + 3] = f2bf(x.w);
    }
    __syncthreads();
    #pragma unroll
    for (int it = 0; it < 2; ++it) {
        int v = tid + it * 256;
        int c = v >> 3, s = v & 7;
        u16 tmp[8];
        #pragma unroll
        for (int i2 = 0; i2 < 8; ++i2) tmp[i2] = T[s * 8 + i2][c];
        *reinterpret_cast<uint4*>(op + (size_t)c * EE + s * 8) = *reinterpret_cast<uint4*>(tmp);
    }
}

// ---------------- Kernel 1: QKV projection (gload_lds, dbuf, counted vmcnt) ----------------
// z=0: q[b][h][t][d]*0.125, z=1: k[b][h][t][d], z=2: vT[b][h][d][t]
__global__ __launch_bounds__(256) void qkv_gemm(
    const u16* __restrict__ dataB, const u16* __restrict__ WqT,
    const u16* __restrict__ WkT, const u16* __restrict__ WvT,
    u16* __restrict__ qws, u16* __restrict__ kws, u16* __restrict__ vtws)
{
    const int z = blockIdx.z;
    const u16* WT = (z == 0) ? WqT : ((z == 1) ? WkT : WvT);
    u16* out = (z == 0) ? qws : ((z == 1) ? kws : vtws);
    const int h  = blockIdx.y;
    const int m0 = blockIdx.x * 128;
    const int b  = m0 / TT;
    const int t0 = m0 % TT;

    __shared__ u16 As[2][128 * 64];   // [t-row][e-slot], swizzled content
    __shared__ u16 Bs[2][64 * 64];    // [d-row][e-slot], swizzled content

    const int tid = threadIdx.x;
    const int l  = tid & 63;
    const int w  = tid >> 6;
    const int wr = w >> 1;
    const int wc = w & 1;
    const int lr = l & 15;
    const int lk = l >> 4;
    const int lrow = l >> 3, lslot = l & 7;

    const u16* Abase = dataB + (size_t)m0 * EE;
    const u16* Bbase = WT + (size_t)h * DD * EE;

    auto stage = [&](int e0, int buf) {
        #pragma unroll
        for (int ii = 0; ii < 4; ++ii) {
            const int i = w * 4 + ii;                  // A loads 0..15, 8 rows each
            const int row = i * 8 + lrow;
            const int sw = lslot ^ (row & 7);
            GLOADLDS16(Abase + (size_t)row * EE + e0 + sw * 8, &As[buf][i * 8 * 64]);
        }
        #pragma unroll
        for (int ii = 0; ii < 2; ++ii) {
            const int i = w * 2 + ii;                  // B loads 0..7
            const int row = i * 8 + lrow;
            const int sw = lslot ^ (row & 7);
            GLOADLDS16(Bbase + (size_t)row * EE + e0 + sw * 8, &Bs[buf][i * 8 * 64]);
        }
    };

    f32x4 acc[4][2];
    for (int i = 0; i < 4; ++i)
        for (int j = 0; j < 2; ++j)
            acc[i][j] = (f32x4){0.f, 0.f, 0.f, 0.f};

    stage(0, 0);
    for (int j = 0; j < 16; ++j) {
        const int cur = j & 1;
        if (j < 15) {
            stage((j + 1) * 64, cur ^ 1);
            asm volatile("s_waitcnt vmcnt(6)" ::: "memory");
        } else {
            asm volatile("s_waitcnt vmcnt(0)" ::: "memory");
        }
        __builtin_amdgcn_sched_barrier(0);
        __builtin_amdgcn_s_barrier();
        __builtin_amdgcn_sched_barrier(0);

        const u16* Ab = &As[cur][0];
        const u16* Bb = &Bs[cur][0];
        #pragma unroll
        for (int kk = 0; kk < 2; ++kk) {
            bf16x8 a[4], bb[2];
            #pragma unroll
            for (int fr = 0; fr < 4; ++fr) {
                const int row = wr * 64 + fr * 16 + lr;
                a[fr] = *reinterpret_cast<const bf16x8*>(Ab + row * 64 + (((kk * 4 + lk) ^ (row & 7)) << 3));
            }
            #pragma unroll
            for (int fc = 0; fc < 2; ++fc) {
                const int row = wc * 32 + fc * 16 + lr;
                bb[fc] = *reinterpret_cast<const bf16x8*>(Bb + row * 64 + (((kk * 4 + lk) ^ (row & 7)) << 3));
            }
            if (z == 2) {
                #pragma unroll
                for (int fr = 0; fr < 4; ++fr)
                    for (int fc = 0; fc < 2; ++fc)
                        acc[fr][fc] = __builtin_amdgcn_mfma_f32_16x16x32_bf16(bb[fc], a[fr], acc[fr][fc], 0, 0, 0);
            } else {
                #pragma unroll
                for (int fr = 0; fr < 4; ++fr)
                    for (int fc = 0; fc < 2; ++fc)
                        acc[fr][fc] = __builtin_amdgcn_mfma_f32_16x16x32_bf16(a[fr], bb[fc], acc[fr][fc], 0, 0, 0);
            }
        }
        __builtin_amdgcn_sched_barrier(0);
        __builtin_amdgcn_s_barrier();
        __builtin_amdgcn_sched_barrier(0);
    }

    if (z == 2) {
        for (int fr = 0; fr < 4; ++fr) {
            int tcol = wr * 64 + fr * 16 + lr;
            for (int fc = 0; fc < 2; ++fc) {
                int drow = wc * 32 + fc * 16 + lk * 4;
                size_t base = (((size_t)(b * HH + h)) * DD + drow) * TT + (t0 + tcol);
                for (int rr = 0; rr < 4; ++rr)
                    out[base + (size_t)rr * TT] = f2bf(acc[fr][fc][rr]);
            }
        }
    } else {
        const float scale = (z == 0) ? 0.125f : 1.0f;
        for (int fr = 0; fr < 4; ++fr) {
            int row = wr * 64 + fr * 16 + lk * 4;
            for (int fc = 0; fc < 2; ++fc) {
                int col = wc * 32 + fc * 16 + lr;
                size_t base = (((size_t)b * HH + h) * TT + (size_t)(t0 + row)) * DD + col;
                for (int rr = 0; rr < 4; ++rr)
                    out[base + (size_t)rr * DD] = f2bf(acc[fr][fc][rr] * scale);
            }
        }
    }
}

// ---------------- Kernel 2: causal flash attention (round-4 + setprio + XCD remap) ----------------
__global__ __launch_bounds__(256) void attn(
    const u16* __restrict__ qws, const u16* __restrict__ kws,
    const u16* __restrict__ vtws, u16* __restrict__ aout)
{
    // bijective remap: all 32 q-blocks of a bh land on the same XCD (L2 KV locality)
    const int L = (int)blockIdx.x + 32 * (int)blockIdx.y;   // 0..2047
    const int xcd = L & 7;
    const int kq = L >> 3;                                  // 0..255
    const int bh = xcd + 8 * (kq >> 5);
    const int qt = 31 - (kq & 31);                          // heaviest first
    const int b = bh >> 4, h = bh & 15;
    const int q0 = qt * 64;

    __shared__ u16 Ks[2][64 * 64];
    __shared__ u16 Vs[2][64 * 64];
    __shared__ u16 Pb[4][16 * 68];

    const int tid = threadIdx.x;
    const int l = tid & 63;
    const int w = tid >> 6;
    const int lr = l & 15, lk = l >> 4;
    const int lrow = l >> 3, lslot = l & 7;

    const size_t kvbase = (size_t)bh * TT * DD;
    const int qb = q0 + w * 16;

    bf16x8 qf[2];
    for (int kk = 0; kk < 2; ++kk)
        qf[kk] = *reinterpret_cast<const bf16x8*>(qws + kvbase + (size_t)(qb + lr) * DD + kk * 32 + lk * 8);
    asm volatile("s_waitcnt vmcnt(0)" ::: "memory");

    auto stage = [&](int jt, int bufi) {
        const int s0 = jt * 64;
        for (int ii = 0; ii < 2; ++ii) {
            const int row = w * 16 + ii * 8 + lrow;
            const int sw = lslot ^ (row & 7);
            const u16* gk = kws + kvbase + (size_t)(s0 + row) * DD + sw * 8;
            GLOADLDS16(gk, &Ks[bufi][(w * 16 + ii * 8) * 64]);
            const u16* gv = vtws + kvbase + (size_t)row * TT + s0 + sw * 8;
            GLOADLDS16(gv, &Vs[bufi][(w * 16 + ii * 8) * 64]);
        }
    };

    f32x4 oacc[4];
    for (int i = 0; i < 4; ++i) oacc[i] = (f32x4){0.f, 0.f, 0.f, 0.f};
    float mrow[4], lsum[4];
    for (int r = 0; r < 4; ++r) { mrow[r] = -INFINITY; lsum[r] = 0.f; }

    const int ntiles = qt + 1;
    stage(0, 0);

    for (int j = 0; j < ntiles; ++j) {
        const int cur = j & 1;
        if (j + 1 < ntiles) {
            stage(j + 1, cur ^ 1);
            asm volatile("s_waitcnt vmcnt(4)" ::: "memory");
        } else {
            asm volatile("s_waitcnt vmcnt(0)" ::: "memory");
        }
        __builtin_amdgcn_sched_barrier(0);
        __builtin_amdgcn_s_barrier();
        __builtin_amdgcn_sched_barrier(0);

        const u16* Kb = &Ks[cur][0];
        const u16* Vb = &Vs[cur][0];

        f32x4 sc[4];
        __builtin_amdgcn_s_setprio(1);
        #pragma unroll
        for (int fc = 0; fc < 4; ++fc) {
            sc[fc] = (f32x4){0.f, 0.f, 0.f, 0.f};
            const int row = fc * 16 + lr;
            const int sw = (row & 7) << 3;
            #pragma unroll
            for (int kk = 0; kk < 2; ++kk) {
                bf16x8 kf = *reinterpret_cast<const bf16x8*>(Kb + row * 64 + ((kk * 32 + lk * 8) ^ sw));
                sc[fc] = __builtin_amdgcn_mfma_f32_16x16x32_bf16(qf[kk], kf, sc[fc], 0, 0, 0);
            }
        }
        __builtin_amdgcn_s_setprio(0);
        if (j == ntiles - 1) {
            #pragma unroll
            for (int fc = 0; fc < 4; ++fc)
                for (int r = 0; r < 4; ++r)
                    if (fc * 16 + lr > w * 16 + lk * 4 + r) sc[fc][r] = -INFINITY;
        }
        float mx[4];
        for (int r = 0; r < 4; ++r)
            mx[r] = fmaxf(fmaxf(sc[0][r], sc[1][r]), fmaxf(sc[2][r], sc[3][r]));
        for (int off = 1; off < 16; off <<= 1)
            for (int r = 0; r < 4; ++r) mx[r] = fmaxf(mx[r], __shfl_xor(mx[r], off, 64));
        float mnew[4], alpha[4];
        for (int r = 0; r < 4; ++r) {
            mnew[r] = fmaxf(mrow[r], mx[r]);
            alpha[r] = exp2f((mrow[r] - mnew[r]) * 1.44269504f);
        }
        float p[4][4], rsum[4];
        for (int r = 0; r < 4; ++r) rsum[r] = 0.f;
        for (int fc = 0; fc < 4; ++fc)
            for (int r = 0; r < 4; ++r) {
                p[fc][r] = exp2f((sc[fc][r] - mnew[r]) * 1.44269504f);
                rsum[r] += p[fc][r];
            }
        for (int off = 1; off < 16; off <<= 1)
            for (int r = 0; r < 4; ++r) rsum[r] += __shfl_xor(rsum[r], off, 64);
        for (int r = 0; r < 4; ++r) {
            lsum[r] = lsum[r] * alpha[r] + rsum[r];
            mrow[r] = mnew[r];
        }
        for (int fc = 0; fc < 4; ++fc)
            for (int r = 0; r < 4; ++r)
                oacc[fc][r] *= alpha[r];
        for (int fc = 0; fc < 4; ++fc)
            for (int r = 0; r < 4; ++r)
                Pb[w][(lk * 4 + r) * 68 + fc * 16 + lr] = f2bf(p[fc][r]);
        bf16x8 pa[2];
        for (int ks = 0; ks < 2; ++ks)
            pa[ks] = *reinterpret_cast<const bf16x8*>(&Pb[w][lr * 68 + ks * 32 + lk * 8]);
        __builtin_amdgcn_s_setprio(1);
        #pragma unroll
        for (int fc = 0; fc < 4; ++fc) {
            const int row = fc * 16 + lr;
            const int sw = (row & 7) << 3;
            #pragma unroll
            for (int ks = 0; ks < 2; ++ks) {
                bf16x8 vf = *reinterpret_cast<const bf16x8*>(Vb + row * 64 + ((ks * 32 + lk * 8) ^ sw));
                oacc[fc] = __builtin_amdgcn_mfma_f32_16x16x32_bf16(pa[ks], vf, oacc[fc], 0, 0, 0);
            }
        }
        __builtin_amdgcn_s_setprio(0);
        __builtin_amdgcn_sched_barrier(0);
        __builtin_amdgcn_s_barrier();
        __builtin_amdgcn_sched_barrier(0);
    }

    for (int fc = 0; fc < 4; ++fc) {
        int dcol = fc * 16 + lr;
        for (int r = 0; r < 4; ++r) {
            int qrow = qb + lk * 4 + r;
            float v = oacc[fc][r] / lsum[r];
            aout[((size_t)b * TT + qrow) * EE + (size_t)h * DD + dcol] = f2bf(v);
        }
    }
}

// ---------------- Kernel 3: output projection (gload_lds, dbuf) ----------------
// A: bf16 [M,E]; WpT: bf16 [n][e]; bp f32; out f32 [M,E]
__global__ __launch_bounds__(256) void proj_gemm(
    const u16* __restrict__ A, const u16* __restrict__ WpT,
    const float* __restrict__ bp, float* __restrict__ out)
{
    const int m0 = blockIdx.x * 128;
    const int n0 = blockIdx.y * 64;

    __shared__ u16 As[2][128 * 64];
    __shared__ u16 Bs[2][64 * 64];

    const int tid = threadIdx.x;
    const int l  = tid & 63;
    const int w  = tid >> 6;
    const int wr = w >> 1;
    const int wc = w & 1;
    const int lr = l & 15;
    const int lk = l >> 4;
    const int lrow = l >> 3, lslot = l & 7;

    const u16* Abase = A + (size_t)m0 * EE;
    const u16* Bbase = WpT + (size_t)n0 * EE;

    auto stage = [&](int e0, int buf) {
        #pragma unroll
        for (int ii = 0; ii < 4; ++ii) {
            const int i = w * 4 + ii;
            const int row = i * 8 + lrow;
            const int sw = lslot ^ (row & 7);
            GLOADLDS16(Abase + (size_t)row * EE + e0 + sw * 8, &As[buf][i * 8 * 64]);
        }
        #pragma unroll
        for (int ii = 0; ii < 2; ++ii) {
            const int i = w * 2 + ii;
            const int row = i * 8 + lrow;
            const int sw = lslot ^ (row & 7);
            GLOADLDS16(Bbase + (size_t)row * EE + e0 + sw * 8, &Bs[buf][i * 8 * 64]);
        }
    };

    f32x4 acc[4][2];
    for (int i = 0; i < 4; ++i)
        for (int j = 0; j < 2; ++j)
            acc[i][j] = (f32x4){0.f, 0.f, 0.f, 0.f};

    stage(0, 0);
    for (int j = 0; j < 16; ++j) {
        const int cur = j & 1;
        if (j < 15) {
            stage((j + 1) * 64, cur ^ 1);
            asm volatile("s_waitcnt vmcnt(6)" ::: "memory");
        } else {
            asm volatile("s_waitcnt vmcnt(0)" ::: "memory");
        }
        __builtin_amdgcn_sched_barrier(0);
        __builtin_amdgcn_s_barrier();
        __builtin_amdgcn_sched_barrier(0);

        const u16* Ab = &As[cur][0];
        const u16* Bb = &Bs[cur][0];
        #pragma unroll
        for (int kk = 0; kk < 2; ++kk) {
            bf16x8 a[4], bb[2];
            #pragma unroll
            for (int fr = 0; fr < 4; ++fr) {
                const int row = wr * 64 + fr * 16 + lr;
                a[fr] = *reinterpret_cast<const bf16x8*>(Ab + row * 64 + (((kk * 4 + lk) ^ (row & 7)) << 3));
            }
            #pragma unroll
            for (int fc = 0; fc < 2; ++fc) {
                const int row = wc * 32 + fc * 16 + lr;
                bb[fc] = *reinterpret_cast<const bf16x8*>(Bb + row * 64 + (((kk * 4 + lk) ^ (row & 7)) << 3));
            }
            #pragma unroll
            for (int fr = 0; fr < 4; ++fr)
                for (int fc = 0; fc < 2; ++fc)
                    acc[fr][fc] = __builtin_amdgcn_mfma_f32_16x16x32_bf16(a[fr], bb[fc], acc[fr][fc], 0, 0, 0);
        }
        __builtin_amdgcn_sched_barrier(0);
        __builtin_amdgcn_s_barrier();
        __builtin_amdgcn_sched_barrier(0);
    }

    for (int fr = 0; fr < 4; ++fr) {
        int row = wr * 64 + fr * 16 + lk * 4;
        for (int fc = 0; fc < 2; ++fc) {
            int col = n0 + wc * 32 + fc * 16 + lr;
            float bias = bp[col];
            for (int rr = 0; rr < 4; ++rr)
                out[((size_t)(m0 + row + rr)) * EE + col] = acc[fr][fc][rr] + bias;
        }
    }
}

extern "C" void kernel_launch(void* const* d_in, const int* in_sizes, int n_in,
                              void* d_out, int out_size, void* d_ws, size_t ws_size,
                              hipStream_t stream) {
    const float* data = (const float*)d_in[0];
    const float* Wq   = (const float*)d_in[1];
    const float* Wk   = (const float*)d_in[2];
    const float* Wv   = (const float*)d_in[3];
    const float* Wp   = (const float*)d_in[4];
    const float* bp   = (const float*)d_in[5];
    float* outp = (float*)d_out;

    const size_t S = (size_t)BI * HH * TT * DD;  // 8,388,608 elems
    const size_t WSZ = (size_t)HH * DD * EE;     // 1,048,576 elems
    u16* qws  = (u16*)d_ws;
    u16* kws  = qws + S;
    u16* vtws = kws + S;          // [B][H][D][T]
    u16* xbuf = vtws + S;         // data_bf16 during qkv, attn-out after
    // WT scratch lives in d_out (dead until proj writes it at the end)
    u16* wqt = (u16*)d_out;
    u16* wkt = wqt + WSZ;
    u16* wvt = wkt + WSZ;
    // WpT reuses qws (dead after attn)
    u16* wpt = qws;

    cvt_data<<<1024, 256, 0, stream>>>(data, xbuf);
    transp_w<<<768, 256, 0, stream>>>(Wq, Wk, Wv, wqt, wkt, wvt);
    qkv_gemm<<<dim3(64, 16, 3), 256, 0, stream>>>(xbuf, wqt, wkt, wvt, qws, kws, vtws);
    attn<<<dim3(32, 64), 256, 0, stream>>>(qws, kws, vtws, xbuf);
    transp_p<<<256, 256, 0, stream>>>(Wp, wpt);
    proj_gemm<<<dim3(64, 16), 256, 0, stream>>>(xbuf, wpt, bp, outp);
}